// Round 5
// baseline (224.682 us; speedup 1.0000x reference)
//
#include <hip/hip_runtime.h>
#include <math.h>

typedef __attribute__((ext_vector_type(4))) float f32x4;
typedef __attribute__((ext_vector_type(8))) short s16x8;

// small-GEMM tile
#define BM 32
#define BN 256
#define BK 64
#define LDS_TILE ((BM + BN) * BK)

// big-GEMM tile
#define BM2 128
#define BK2 64
#define NBUF 3
#define KFULL 8192
#define ZSPLIT 4
#define KQ (KFULL / ZSPLIT)  // 2048

__device__ __forceinline__ unsigned short f2bf(float f) {
  unsigned int u = __float_as_uint(f);
  u += 0x7fffu + ((u >> 16) & 1u);
  return (unsigned short)(u >> 16);
}
__device__ __forceinline__ float bf2f(unsigned short h) {
  unsigned int u = ((unsigned int)h) << 16;
  return __uint_as_float(u);
}

__device__ __forceinline__ void gload16(const void* g, void* l) {
  __builtin_amdgcn_global_load_lds(
      (const __attribute__((address_space(1))) void*)g,
      (__attribute__((address_space(3))) void*)l, 16, 0, 0);
}

// F-layout halfword offset for element (k=node, h=hid):
// F[k>>6][h>>4][(k>>5)&1][h&15][(k>>3)&3][k&7]
__device__ __forceinline__ size_t f_off(int k, int h) {
  return (size_t)(k >> 6) * 16384 + (size_t)(h >> 4) * 1024 +
         (size_t)((k >> 5) & 1) * 512 + (size_t)(h & 15) * 32 +
         (size_t)((k >> 3) & 3) * 8;
}

// ---------------- merged weight transposes: W[K][M] -> WT[M][K] fp32 ----------------
__global__ __launch_bounds__(256) void transW(const float* __restrict__ W1,
                                              const float* __restrict__ W2,
                                              float* __restrict__ W1T,
                                              float* __restrict__ W2T) {
  __shared__ float t[64][65];
  int bx = blockIdx.x;
  const float* in;
  float* out;
  int K, M;
  if (bx < 32) { in = W1; out = W1T; K = 512; M = 256; }
  else { bx -= 32; in = W2; out = W2T; K = 256; M = 256; }
  int tiles_m = M >> 6;
  int tk = bx / tiles_m, tm = bx % tiles_m;
  int k0 = tk * 64, m0 = tm * 64;
  int ty = threadIdx.x >> 4, tx = threadIdx.x & 15;
#pragma unroll
  for (int i = 0; i < 4; ++i) {
    f32x4 v = *(const f32x4*)(in + (size_t)(k0 + ty + 16 * i) * M + m0 + tx * 4);
    t[ty + 16 * i][tx * 4 + 0] = v[0];
    t[ty + 16 * i][tx * 4 + 1] = v[1];
    t[ty + 16 * i][tx * 4 + 2] = v[2];
    t[ty + 16 * i][tx * 4 + 3] = v[3];
  }
  __syncthreads();
#pragma unroll
  for (int i = 0; i < 4; ++i) {
    int m = ty + 16 * i;
    f32x4 v = {t[tx * 4 + 0][m], t[tx * 4 + 1][m], t[tx * 4 + 2][m], t[tx * 4 + 3][m]};
    *(f32x4*)(out + (size_t)(m0 + m) * K + k0 + tx * 4) = v;
  }
}

// ---------------- small GEMM: C[M,N] = AT[M,K] * BT[N,K]^T ----------------
// EPI 3: bf16 out = acc + bias[row]                          (gemm3: h1)
// EPI 4: F-layout out = (acc + bias[row])*dinv[col]          (gemm6 -> F2)
template <bool BF32, int EPI>
__device__ __forceinline__ void gemm_small(int bx, unsigned short* ldsb,
                                           const float* __restrict__ AT,
                                           const void* __restrict__ BTp,
                                           void* __restrict__ outp,
                                           const float* __restrict__ bias,
                                           const float* __restrict__ dinv,
                                           int M, int N, int K) {
  const int tid = threadIdx.x;
  const int m0 = (bx & (M / BM - 1)) * BM;
  const int n0 = (bx / (M / BM)) * BN;
  const int sr = tid >> 3;
  const int sc = (tid & 7) * 8;
  const float* Bf = (const float*)BTp;
  const unsigned short* Bh = (const unsigned short*)BTp;

  f32x4 a_f[2];
  f32x4 b_f[8][2];
  s16x8 b_h[8];

  auto stage_load = [&](int k0) {
    const float* pa = AT + (size_t)(m0 + sr) * K + k0 + sc;
    a_f[0] = *(const f32x4*)(pa);
    a_f[1] = *(const f32x4*)(pa + 4);
#pragma unroll
    for (int it = 0; it < 8; ++it) {
      int n = n0 + it * 32 + sr;
      if (BF32) {
        const float* p = Bf + (size_t)n * K + k0 + sc;
        b_f[it][0] = *(const f32x4*)(p);
        b_f[it][1] = *(const f32x4*)(p + 4);
      } else {
        b_h[it] = *(const s16x8*)(Bh + (size_t)n * K + k0 + sc);
      }
    }
  };

  auto stage_write = [&](int buf) {
    unsigned short* L = ldsb + buf * LDS_TILE;
    {
      s16x8 v;
#pragma unroll
      for (int j = 0; j < 8; ++j) v[j] = (short)f2bf(j < 4 ? a_f[0][j] : a_f[1][j - 4]);
      int idx = (sr * BK + sc) ^ ((sr & 7) << 3);
      *(s16x8*)(L + idx) = v;
    }
#pragma unroll
    for (int it = 0; it < 8; ++it) {
      int r = it * 32 + sr;
      s16x8 w;
      if (BF32) {
#pragma unroll
        for (int j = 0; j < 8; ++j)
          w[j] = (short)f2bf(j < 4 ? b_f[it][0][j] : b_f[it][1][j - 4]);
      } else {
        w = b_h[it];
      }
      int idx = BM * BK + ((r * BK + sc) ^ ((r & 7) << 3));
      *(s16x8*)(L + idx) = w;
    }
  };

  const int lane = tid & 63;
  const int wv = tid >> 6;
  const int g = lane >> 4, lr = lane & 15;

  int aidx[2][2], bidx[4][2];
#pragma unroll
  for (int m = 0; m < 2; ++m)
#pragma unroll
    for (int ks = 0; ks < 2; ++ks) {
      int r = m * 16 + lr;
      aidx[m][ks] = (r * BK + ks * 32 + g * 8) ^ ((r & 7) << 3);
    }
#pragma unroll
  for (int n = 0; n < 4; ++n)
#pragma unroll
    for (int ks = 0; ks < 2; ++ks) {
      int r = wv * 64 + n * 16 + lr;
      bidx[n][ks] = BM * BK + ((r * BK + ks * 32 + g * 8) ^ ((r & 7) << 3));
    }

  f32x4 acc[2][4];
#pragma unroll
  for (int m = 0; m < 2; ++m)
#pragma unroll
    for (int n = 0; n < 4; ++n) {
      f32x4 z = {0.f, 0.f, 0.f, 0.f};
      acc[m][n] = z;
    }

  auto compute = [&](int buf) {
    const unsigned short* L = ldsb + buf * LDS_TILE;
    s16x8 af[2][2], bfr[4][2];
#pragma unroll
    for (int m = 0; m < 2; ++m)
#pragma unroll
      for (int ks = 0; ks < 2; ++ks) af[m][ks] = *(const s16x8*)(L + aidx[m][ks]);
#pragma unroll
    for (int n = 0; n < 4; ++n)
#pragma unroll
      for (int ks = 0; ks < 2; ++ks) bfr[n][ks] = *(const s16x8*)(L + bidx[n][ks]);
#pragma unroll
    for (int m = 0; m < 2; ++m)
#pragma unroll
      for (int n = 0; n < 4; ++n)
#pragma unroll
        for (int ks = 0; ks < 2; ++ks)
          acc[m][n] = __builtin_amdgcn_mfma_f32_16x16x32_bf16(af[m][ks], bfr[n][ks],
                                                              acc[m][n], 0, 0, 0);
  };

  stage_load(0);
  stage_write(0);
  __syncthreads();
  int cur = 0;
  const int nt = K / BK;
  for (int t = 0; t < nt; ++t) {
    if (t + 1 < nt) stage_load((t + 1) * BK);
    compute(cur);
    if (t + 1 < nt) {
      stage_write(cur ^ 1);
      __syncthreads();
      cur ^= 1;
    }
  }

  if constexpr (EPI == 3) {
#pragma unroll
    for (int m = 0; m < 2; ++m)
#pragma unroll
      for (int n = 0; n < 4; ++n) {
        int col = n0 + wv * 64 + n * 16 + lr;
#pragma unroll
        for (int r = 0; r < 4; ++r) {
          int row = m0 + m * 16 + g * 4 + r;
          ((unsigned short*)outp)[(size_t)row * N + col] = f2bf(acc[m][n][r] + bias[row]);
        }
      }
  } else {
    // EPI 4: bf16 vals -> LDS tile T[32][264] -> F-layout global
    __syncthreads();
    unsigned short* T = ldsb;
#pragma unroll
    for (int m = 0; m < 2; ++m)
#pragma unroll
      for (int n = 0; n < 4; ++n) {
        int cl = wv * 64 + n * 16 + lr;
        float dv = dinv[n0 + cl];
#pragma unroll
        for (int r = 0; r < 4; ++r) {
          int rl = m * 16 + g * 4 + r;
          T[rl * 264 + cl] = f2bf((acc[m][n][r] + bias[m0 + rl]) * dv);
        }
      }
    __syncthreads();
    int h_loc = tid >> 3, c8 = tid & 7;
#pragma unroll
    for (int p = 0; p < 4; ++p) {
      int i_loc = p * 64 + c8 * 8;
      s16x8 v = *(const s16x8*)(T + h_loc * 264 + i_loc);
      *(s16x8*)((unsigned short*)outp + f_off(n0 + i_loc, m0 + h_loc)) = v;
    }
  }
}

// ---------------- prep: gemm3 blocks [0,256) + adj conv/rowsum blocks [256,4352) ----------------
__global__ __launch_bounds__(256) void prep(const float* __restrict__ adj,
                                            const float* __restrict__ x,
                                            const float* __restrict__ W1T,
                                            const float* __restrict__ b1,
                                            unsigned short* __restrict__ adjh,
                                            float* __restrict__ dinv,
                                            unsigned short* __restrict__ h1) {
  __shared__ unsigned short lds[2 * LDS_TILE];
  int bx = blockIdx.x;
  if (bx < 256) {
    gemm_small<true, 3>(bx, lds, W1T, x, h1, b1, nullptr, 256, 8192, 512);
    return;
  }
  bx -= 256;
  float* smf = (float*)lds;
  const int tid = threadIdx.x;
  float psum[2];
#pragma unroll
  for (int rr = 0; rr < 2; ++rr) {
    int row = bx * 2 + rr;
    const float* src = adj + (size_t)row * 8192;
    unsigned short* dst = adjh + (size_t)row * 8192;
    float s = 0.f;
    for (int c = tid * 8; c < 8192; c += 2048) {
      f32x4 v0 = __builtin_nontemporal_load((const f32x4*)(src + c));
      f32x4 v1 = __builtin_nontemporal_load((const f32x4*)(src + c + 4));
      s += v0[0] + v0[1] + v0[2] + v0[3] + v1[0] + v1[1] + v1[2] + v1[3];
      if (row >= c && row < c + 8) {
        int d = row - c;
        if (d < 4) v0[d] += 1.f; else v1[d - 4] += 1.f;
      }
      s16x8 o;
#pragma unroll
      for (int j = 0; j < 4; ++j) {
        o[j] = (short)f2bf(v0[j]);
        o[j + 4] = (short)f2bf(v1[j]);
      }
      *(s16x8*)(dst + c) = o;
    }
    psum[rr] = s;
  }
#pragma unroll
  for (int rr = 0; rr < 2; ++rr) {
    float s = psum[rr];
#pragma unroll
    for (int off = 32; off > 0; off >>= 1) s += __shfl_down(s, off, 64);
    if ((tid & 63) == 0) smf[rr * 4 + (tid >> 6)] = s;
  }
  __syncthreads();
  if (tid < 2) {
    float tot = smf[tid * 4] + smf[tid * 4 + 1] + smf[tid * 4 + 2] + smf[tid * 4 + 3];
    dinv[bx * 2 + tid] = rsqrtf(tot + 1.0f);
  }
}

// ---------------- scale_hs: F1 = Flayout(bf16(h1 * dinv[node])) ----------------
__global__ __launch_bounds__(256) void scale_hs(const unsigned short* __restrict__ h1,
                                                const float* __restrict__ dinv,
                                                unsigned short* __restrict__ F1) {
  size_t e = ((size_t)blockIdx.x * 256 + threadIdx.x) * 8;
  int h = (int)(e >> 13);
  int k = (int)(e & 8191);
  s16x8 v = *(const s16x8*)(h1 + e);
  f32x4 d0 = *(const f32x4*)(dinv + k);
  f32x4 d1 = *(const f32x4*)(dinv + k + 4);
  s16x8 o;
#pragma unroll
  for (int j = 0; j < 4; ++j) {
    o[j] = (short)f2bf(bf2f((unsigned short)v[j]) * d0[j]);
    o[j + 4] = (short)f2bf(bf2f((unsigned short)v[j + 4]) * d1[j]);
  }
  *(s16x8*)(F1 + f_off(k, h)) = o;
}

// ---------------- big GEMM (split-K=4): P[z] = adjh @ hs^T partials ----------------
// A via global_load_lds->LDS (NBUF=3); B via direct L2 fragment loads from F (reg dbuf).
__global__ __launch_bounds__(512) void gemm_big(const unsigned short* __restrict__ A,
                                                const unsigned short* __restrict__ F,
                                                float* __restrict__ P) {
  __shared__ unsigned short ldsA[NBUF * BM2 * BK2];  // 48 KB
  const int tid = threadIdx.x;
  const int mt = blockIdx.x & 63;
  const int z = blockIdx.x >> 6;
  const int m0 = mt * BM2;

  const int w = tid >> 6, l = tid & 63;
  const int lrow = l >> 3;
  const int swz = ((l & 7) * 16) ^ (lrow << 4);  // pre-swizzled byte-in-row (matches read XOR)

  const char* Asrc[2];
#pragma unroll
  for (int j = 0; j < 2; ++j) {
    int ra = w * 16 + j * 8 + lrow;
    Asrc[j] = (const char*)(A + (size_t)(m0 + ra) * KFULL + (size_t)z * KQ) + swz;
  }
  auto stageA = [&](int buf, int t) {  // 2 global_load_lds per thread
    unsigned short* L = ldsA + buf * (BM2 * BK2);
#pragma unroll
    for (int j = 0; j < 2; ++j)
      gload16(Asrc[j] + (size_t)t * (BK2 * 2), L + (w * 16 + j * 8) * 64);
  };

  const int wr = w >> 2, wc = w & 3;
  const int g = l >> 4, lr = l & 15;
  int aidx[4][2];
#pragma unroll
  for (int m = 0; m < 4; ++m)
#pragma unroll
    for (int ks = 0; ks < 2; ++ks) {
      int r = wr * 64 + m * 16 + lr;
      aidx[m][ks] = r * 64 + ((ks * 32 + g * 8) ^ ((r & 7) << 3));
    }

  // B fragment base: wave wc covers ct = wc*4 + n; lane adds lr*32 + g*8
  const unsigned short* fp = F + (size_t)z * (KQ / 64) * 16384 + wc * 4096 + lr * 32 + g * 8;

  f32x4 acc[4][4];
#pragma unroll
  for (int m = 0; m < 4; ++m)
#pragma unroll
    for (int n = 0; n < 4; ++n) {
      f32x4 zz = {0.f, 0.f, 0.f, 0.f};
      acc[m][n] = zz;
    }

  s16x8 bA[4][2], bB[4][2], af[4][2];

  auto loadB = [&](s16x8 (&dst)[4][2], const unsigned short* base) {
#pragma unroll
    for (int n = 0; n < 4; ++n)
#pragma unroll
      for (int ks = 0; ks < 2; ++ks)
        dst[n][ks] = *(const s16x8*)(base + n * 1024 + ks * 512);
  };

  stageA(0, 0);
  stageA(1, 1);
  stageA(2, 2);
  loadB(bA, fp);

  const int nt = KQ / BK2;  // 32
  int cur = 0;
  auto body = [&](int t, s16x8 (&bc)[4][2], s16x8 (&bn)[4][2]) {
    // drain A(t): at most {A(t+1),A(t+2) [4], B(t) [8]} newer
    if (t + 2 < nt)      asm volatile("s_waitcnt vmcnt(12)" ::: "memory");
    else if (t + 1 < nt) asm volatile("s_waitcnt vmcnt(10)" ::: "memory");
    else                 asm volatile("s_waitcnt vmcnt(8)" ::: "memory");
    __builtin_amdgcn_sched_barrier(0);
    asm volatile("s_barrier" ::: "memory");
    __builtin_amdgcn_sched_barrier(0);

    const unsigned short* L = ldsA + cur * (BM2 * BK2);
#pragma unroll
    for (int m = 0; m < 4; ++m)
#pragma unroll
      for (int ks = 0; ks < 2; ++ks) af[m][ks] = *(const s16x8*)(L + aidx[m][ks]);
    if (t + 1 < nt) loadB(bn, fp + 16384);
    __builtin_amdgcn_s_setprio(1);
#pragma unroll
    for (int m = 0; m < 4; ++m)
#pragma unroll
      for (int n = 0; n < 4; ++n)
#pragma unroll
        for (int ks = 0; ks < 2; ++ks)
          acc[m][n] = __builtin_amdgcn_mfma_f32_16x16x32_bf16(af[m][ks], bc[n][ks],
                                                              acc[m][n], 0, 0, 0);
    __builtin_amdgcn_s_setprio(0);

    __builtin_amdgcn_sched_barrier(0);
    asm volatile("s_barrier" ::: "memory");  // all waves done reading ldsA[cur]
    __builtin_amdgcn_sched_barrier(0);
    if (t + 3 < nt) stageA(cur, t + 3);
    fp += 16384;
    cur = (cur == NBUF - 1) ? 0 : cur + 1;
  };
  for (int t = 0; t < nt; t += 2) {
    body(t, bA, bB);
    body(t + 1, bB, bA);
  }

  float* Pz = P + (size_t)z * 8192 * 256;
#pragma unroll
  for (int m = 0; m < 4; ++m)
#pragma unroll
    for (int n = 0; n < 4; ++n) {
      int col = wc * 64 + n * 16 + lr;
#pragma unroll
      for (int r = 0; r < 4; ++r) {
        int row = m0 + wr * 64 + m * 16 + g * 4 + r;
        Pz[(size_t)row * 256 + col] = acc[m][n][r];
      }
    }
}

// ---------------- reduce1: hln = LN(GELU((ΣPz)*dinv[row])), bf16 out ----------------
__global__ __launch_bounds__(256) void reduce_ln(const float* __restrict__ P,
                                                 const float* __restrict__ dinv,
                                                 const float* __restrict__ gamma,
                                                 const float* __restrict__ beta,
                                                 unsigned short* __restrict__ hln) {
  const size_t ZSTR = (size_t)8192 * 256;
  int row = blockIdx.x * 4 + (threadIdx.x >> 6);
  int l = threadIdx.x & 63;
  const float* p = P + (size_t)row * 256 + l * 4;
  f32x4 a = *(const f32x4*)p;
  f32x4 b = *(const f32x4*)(p + ZSTR);
  f32x4 c = *(const f32x4*)(p + 2 * ZSTR);
  f32x4 d = *(const f32x4*)(p + 3 * ZSTR);
  float di = dinv[row];
  float gl[4];
  float s = 0.f, q = 0.f;
#pragma unroll
  for (int j = 0; j < 4; ++j) {
    float v = (a[j] + b[j] + c[j] + d[j]) * di;
    float gv = 0.5f * v * (1.0f + erff(v * 0.70710678118654752440f));
    gl[j] = gv;
    s += gv;
    q += gv * gv;
  }
#pragma unroll
  for (int off = 1; off < 64; off <<= 1) {
    s += __shfl_xor(s, off, 64);
    q += __shfl_xor(q, off, 64);
  }
  float mu = s * (1.0f / 256.0f);
  float var = q * (1.0f / 256.0f) - mu * mu;
  float rs = rsqrtf(fmaxf(var, 0.f) + 1e-6f);
  f32x4 gm = *(const f32x4*)(gamma + l * 4);
  f32x4 bt = *(const f32x4*)(beta + l * 4);
  unsigned short o4[4];
#pragma unroll
  for (int j = 0; j < 4; ++j)
    o4[j] = f2bf((gl[j] - mu) * rs * gm[j] + bt[j]);
  *(unsigned long long*)(hln + (size_t)row * 256 + l * 4) =
      *(const unsigned long long*)o4;
}

// ---------------- reduce2: out fp32 = (ΣPz)*dinv[row] ----------------
__global__ __launch_bounds__(256) void reduce_sc(const float* __restrict__ P,
                                                 const float* __restrict__ dinv,
                                                 float* __restrict__ out) {
  const size_t ZSTR = (size_t)8192 * 256;
  size_t i = ((size_t)blockIdx.x * 256 + threadIdx.x) * 4;
  int row = (int)(i >> 8);
  f32x4 a = *(const f32x4*)(P + i);
  f32x4 b = *(const f32x4*)(P + ZSTR + i);
  f32x4 c = *(const f32x4*)(P + 2 * ZSTR + i);
  f32x4 d = *(const f32x4*)(P + 3 * ZSTR + i);
  float di = dinv[row];
  f32x4 o;
#pragma unroll
  for (int j = 0; j < 4; ++j) o[j] = (a[j] + b[j] + c[j] + d[j]) * di;
  *(f32x4*)(out + i) = o;
}

// ---------------- GEMM6: F2 = Flayout(bf16((hln @ W2 + b2)^T * dinv[col])) ----------------
__global__ __launch_bounds__(256) void gemm6_k(const float* __restrict__ W2T,
                                               const unsigned short* __restrict__ hln,
                                               unsigned short* __restrict__ F2,
                                               const float* __restrict__ b2,
                                               const float* __restrict__ dinv) {
  __shared__ unsigned short lds[2 * LDS_TILE];
  gemm_small<false, 4>(blockIdx.x, lds, W2T, hln, F2, b2, dinv, 256, 8192, 256);
}

// ---------------- launch ----------------
extern "C" void kernel_launch(void* const* d_in, const int* in_sizes, int n_in,
                              void* d_out, int out_size, void* d_ws, size_t ws_size,
                              hipStream_t stream) {
  (void)in_sizes; (void)n_in; (void)out_size; (void)ws_size;
  const float* x     = (const float*)d_in[0];
  const float* adj   = (const float*)d_in[1];
  const float* W1    = (const float*)d_in[2];
  const float* b1    = (const float*)d_in[3];
  const float* W2    = (const float*)d_in[4];
  const float* b2    = (const float*)d_in[5];
  const float* gamma = (const float*)d_in[6];
  const float* beta  = (const float*)d_in[7];
  float* out = (float*)d_out;

  char* ws = (char*)d_ws;
  float* dinv          = (float*)ws;                           // 32 KB
  float* W1T           = (float*)(ws + (64 << 10));            // 512 KB [256][512]
  float* W2T           = (float*)(ws + (640 << 10));           // 256 KB [256][256]
  unsigned short* h1   = (unsigned short*)(ws + (1 << 20));    // 4 MB [256][8192] (pre-dinv)
  unsigned short* F1   = (unsigned short*)(ws + (8 << 20));    // 4 MB F-layout hs1
  unsigned short* hln  = (unsigned short*)(ws + (16 << 20));   // 4 MB [8192][256]
  unsigned short* F2   = (unsigned short*)(ws + (24 << 20));   // 4 MB F-layout hs2
  float* P             = (float*)(ws + (32 << 20));            // 32 MB [4][8192][256]
  unsigned short* adjh = (unsigned short*)(ws + (64 << 20));   // 128 MB [8192][8192] (adj+I)

  // 0) weight transposes (merged)
  transW<<<48, 256, 0, stream>>>(W1, W2, W1T, W2T);
  // 1) gemm3 (h1 bf16) + adj->bf16(+I) + rowsum->dinv, fused
  prep<<<4352, 256, 0, stream>>>(adj, x, W1T, b1, adjh, dinv, h1);
  // 2) F1 = Flayout(h1 * dinv[node])
  scale_hs<<<1024, 256, 0, stream>>>(h1, dinv, F1);
  // 3) P = split-K=4 partials of (adj+I) @ hs1
  gemm_big<<<256, 512, 0, stream>>>(adjh, F1, P);
  // 4) hln = LN(GELU((ΣPz)*dinv[row]))
  reduce_ln<<<2048, 256, 0, stream>>>(P, dinv, gamma, beta, hln);
  // 5) F2 = Flayout((hln @ W2 + b2)^T * dinv[node])
  gemm6_k<<<256, 256, 0, stream>>>(W2T, hln, F2, b2, dinv);
  // 6) P = split-K=4 partials of (adj+I) @ hs2
  gemm_big<<<256, 512, 0, stream>>>(adjh, F2, P);
  // 7) out = (ΣPz)*dinv[row]
  reduce_sc<<<2048, 256, 0, stream>>>(P, dinv, out);
}

// Round 6
// 206.469 us; speedup vs baseline: 1.0882x; 1.0882x over previous
//
#include <hip/hip_runtime.h>
#include <math.h>

typedef __attribute__((ext_vector_type(4))) float f32x4;
typedef __attribute__((ext_vector_type(8))) short s16x8;

// small-GEMM tile
#define BM 32
#define BN 256
#define BK 64
#define LDS_TILE ((BM + BN) * BK)

// big-GEMM tile
#define BM2 128
#define BK2 64
#define KFULL 8192
#define ZSPLIT 4
#define KQ (KFULL / ZSPLIT)   // 2048
#define BUFHW 24576           // (128+256)*64 halfwords per buffer
#define DVHW 49152            // dinv table offset (halfwords)

__device__ __forceinline__ unsigned short f2bf(float f) {
  unsigned int u = __float_as_uint(f);
  u += 0x7fffu + ((u >> 16) & 1u);
  return (unsigned short)(u >> 16);
}
__device__ __forceinline__ float bf2f(unsigned short h) {
  unsigned int u = ((unsigned int)h) << 16;
  return __uint_as_float(u);
}

__device__ __forceinline__ void gload16(const void* g, void* l) {
  __builtin_amdgcn_global_load_lds(
      (const __attribute__((address_space(1))) void*)g,
      (__attribute__((address_space(3))) void*)l, 16, 0, 0);
}

// ---------------- merged weight transposes: W[K][M] -> WT[M][K] fp32 ----------------
__global__ __launch_bounds__(256) void transW(const float* __restrict__ W1,
                                              const float* __restrict__ W2,
                                              float* __restrict__ W1T,
                                              float* __restrict__ W2T) {
  __shared__ float t[64][65];
  int bx = blockIdx.x;
  const float* in;
  float* out;
  int K, M;
  if (bx < 32) { in = W1; out = W1T; K = 512; M = 256; }
  else { bx -= 32; in = W2; out = W2T; K = 256; M = 256; }
  int tiles_m = M >> 6;
  int tk = bx / tiles_m, tm = bx % tiles_m;
  int k0 = tk * 64, m0 = tm * 64;
  int ty = threadIdx.x >> 4, tx = threadIdx.x & 15;
#pragma unroll
  for (int i = 0; i < 4; ++i) {
    f32x4 v = *(const f32x4*)(in + (size_t)(k0 + ty + 16 * i) * M + m0 + tx * 4);
    t[ty + 16 * i][tx * 4 + 0] = v[0];
    t[ty + 16 * i][tx * 4 + 1] = v[1];
    t[ty + 16 * i][tx * 4 + 2] = v[2];
    t[ty + 16 * i][tx * 4 + 3] = v[3];
  }
  __syncthreads();
#pragma unroll
  for (int i = 0; i < 4; ++i) {
    int m = ty + 16 * i;
    f32x4 v = {t[tx * 4 + 0][m], t[tx * 4 + 1][m], t[tx * 4 + 2][m], t[tx * 4 + 3][m]};
    *(f32x4*)(out + (size_t)(m0 + m) * K + k0 + tx * 4) = v;
  }
}

// ---------------- small GEMM: C[M,N] = AT[M,K] * BT[N,K]^T ----------------
// EPI 3: bf16 out = acc + bias[row]             (gemm3: h1, no dinv yet)
// EPI 1: bf16 out = (acc + bias[row])*dinv[col] (gemm6 -> hs2T)
template <bool BF32, int EPI>
__device__ __forceinline__ void gemm_small(int bx, unsigned short* ldsb,
                                           const float* __restrict__ AT,
                                           const void* __restrict__ BTp,
                                           void* __restrict__ outp,
                                           const float* __restrict__ bias,
                                           const float* __restrict__ dinv,
                                           int M, int N, int K) {
  const int tid = threadIdx.x;
  const int m0 = (bx & (M / BM - 1)) * BM;
  const int n0 = (bx / (M / BM)) * BN;
  const int sr = tid >> 3;
  const int sc = (tid & 7) * 8;
  const float* Bf = (const float*)BTp;
  const unsigned short* Bh = (const unsigned short*)BTp;

  f32x4 a_f[2];
  f32x4 b_f[8][2];
  s16x8 b_h[8];

  auto stage_load = [&](int k0) {
    const float* pa = AT + (size_t)(m0 + sr) * K + k0 + sc;
    a_f[0] = *(const f32x4*)(pa);
    a_f[1] = *(const f32x4*)(pa + 4);
#pragma unroll
    for (int it = 0; it < 8; ++it) {
      int n = n0 + it * 32 + sr;
      if (BF32) {
        const float* p = Bf + (size_t)n * K + k0 + sc;
        b_f[it][0] = *(const f32x4*)(p);
        b_f[it][1] = *(const f32x4*)(p + 4);
      } else {
        b_h[it] = *(const s16x8*)(Bh + (size_t)n * K + k0 + sc);
      }
    }
  };

  auto stage_write = [&](int buf) {
    unsigned short* L = ldsb + buf * LDS_TILE;
    {
      s16x8 v;
#pragma unroll
      for (int j = 0; j < 8; ++j) v[j] = (short)f2bf(j < 4 ? a_f[0][j] : a_f[1][j - 4]);
      int idx = (sr * BK + sc) ^ ((sr & 7) << 3);
      *(s16x8*)(L + idx) = v;
    }
#pragma unroll
    for (int it = 0; it < 8; ++it) {
      int r = it * 32 + sr;
      s16x8 w;
      if (BF32) {
#pragma unroll
        for (int j = 0; j < 8; ++j)
          w[j] = (short)f2bf(j < 4 ? b_f[it][0][j] : b_f[it][1][j - 4]);
      } else {
        w = b_h[it];
      }
      int idx = BM * BK + ((r * BK + sc) ^ ((r & 7) << 3));
      *(s16x8*)(L + idx) = w;
    }
  };

  const int lane = tid & 63;
  const int wv = tid >> 6;
  const int g = lane >> 4, lr = lane & 15;

  int aidx[2][2], bidx[4][2];
#pragma unroll
  for (int m = 0; m < 2; ++m)
#pragma unroll
    for (int ks = 0; ks < 2; ++ks) {
      int r = m * 16 + lr;
      aidx[m][ks] = (r * BK + ks * 32 + g * 8) ^ ((r & 7) << 3);
    }
#pragma unroll
  for (int n = 0; n < 4; ++n)
#pragma unroll
    for (int ks = 0; ks < 2; ++ks) {
      int r = wv * 64 + n * 16 + lr;
      bidx[n][ks] = BM * BK + ((r * BK + ks * 32 + g * 8) ^ ((r & 7) << 3));
    }

  f32x4 acc[2][4];
#pragma unroll
  for (int m = 0; m < 2; ++m)
#pragma unroll
    for (int n = 0; n < 4; ++n) {
      f32x4 z = {0.f, 0.f, 0.f, 0.f};
      acc[m][n] = z;
    }

  auto compute = [&](int buf) {
    const unsigned short* L = ldsb + buf * LDS_TILE;
    s16x8 af[2][2], bfr[4][2];
#pragma unroll
    for (int m = 0; m < 2; ++m)
#pragma unroll
      for (int ks = 0; ks < 2; ++ks) af[m][ks] = *(const s16x8*)(L + aidx[m][ks]);
#pragma unroll
    for (int n = 0; n < 4; ++n)
#pragma unroll
      for (int ks = 0; ks < 2; ++ks) bfr[n][ks] = *(const s16x8*)(L + bidx[n][ks]);
#pragma unroll
    for (int m = 0; m < 2; ++m)
#pragma unroll
      for (int n = 0; n < 4; ++n)
#pragma unroll
        for (int ks = 0; ks < 2; ++ks)
          acc[m][n] = __builtin_amdgcn_mfma_f32_16x16x32_bf16(af[m][ks], bfr[n][ks],
                                                              acc[m][n], 0, 0, 0);
  };

  stage_load(0);
  stage_write(0);
  __syncthreads();
  int cur = 0;
  const int nt = K / BK;
  for (int t = 0; t < nt; ++t) {
    if (t + 1 < nt) stage_load((t + 1) * BK);
    compute(cur);
    if (t + 1 < nt) {
      stage_write(cur ^ 1);
      __syncthreads();
      cur ^= 1;
    }
  }

#pragma unroll
  for (int m = 0; m < 2; ++m)
#pragma unroll
    for (int n = 0; n < 4; ++n) {
      int col = n0 + wv * 64 + n * 16 + lr;
#pragma unroll
      for (int r = 0; r < 4; ++r) {
        int row = m0 + m * 16 + g * 4 + r;
        float v = acc[m][n][r];
        if constexpr (EPI == 3) {
          ((unsigned short*)outp)[(size_t)row * N + col] = f2bf(v + bias[row]);
        } else {
          ((unsigned short*)outp)[(size_t)row * N + col] = f2bf((v + bias[row]) * dinv[col]);
        }
      }
    }
}

// ---------------- prep: gemm3 blocks [0,256) + adj conv/rowsum blocks [256,4352) ----------------
__global__ __launch_bounds__(256) void prep(const float* __restrict__ adj,
                                            const float* __restrict__ x,
                                            const float* __restrict__ W1T,
                                            const float* __restrict__ b1,
                                            unsigned short* __restrict__ adjh,
                                            float* __restrict__ dinv,
                                            unsigned short* __restrict__ h1) {
  __shared__ unsigned short lds[2 * LDS_TILE];
  int bx = blockIdx.x;
  if (bx < 256) {
    gemm_small<true, 3>(bx, lds, W1T, x, h1, b1, nullptr, 256, 8192, 512);
    return;
  }
  bx -= 256;
  float* smf = (float*)lds;
  const int tid = threadIdx.x;
  float psum[2];
#pragma unroll
  for (int rr = 0; rr < 2; ++rr) {
    int row = bx * 2 + rr;
    const float* src = adj + (size_t)row * 8192;
    unsigned short* dst = adjh + (size_t)row * 8192;
    float s = 0.f;
    for (int c = tid * 8; c < 8192; c += 2048) {
      f32x4 v0 = __builtin_nontemporal_load((const f32x4*)(src + c));
      f32x4 v1 = __builtin_nontemporal_load((const f32x4*)(src + c + 4));
      s += v0[0] + v0[1] + v0[2] + v0[3] + v1[0] + v1[1] + v1[2] + v1[3];
      if (row >= c && row < c + 8) {  // identity added AFTER summing (deg = rowsum+1)
        int d = row - c;
        if (d < 4) v0[d] += 1.f; else v1[d - 4] += 1.f;
      }
      s16x8 o;
#pragma unroll
      for (int j = 0; j < 4; ++j) {
        o[j] = (short)f2bf(v0[j]);
        o[j + 4] = (short)f2bf(v1[j]);
      }
      *(s16x8*)(dst + c) = o;
    }
    psum[rr] = s;
  }
#pragma unroll
  for (int rr = 0; rr < 2; ++rr) {
    float s = psum[rr];
#pragma unroll
    for (int off = 32; off > 0; off >>= 1) s += __shfl_down(s, off, 64);
    if ((tid & 63) == 0) smf[rr * 4 + (tid >> 6)] = s;
  }
  __syncthreads();
  if (tid < 2) {
    float tot = smf[tid * 4] + smf[tid * 4 + 1] + smf[tid * 4 + 2] + smf[tid * 4 + 3];
    dinv[bx * 2 + tid] = rsqrtf(tot + 1.0f);
  }
}

// ---------------- big GEMM (split-K=4): P[z] = adjh @ B^T partials ----------------
// 1 barrier per K-step, NBUF=2, stage issued BEFORE the MFMA cluster.
// SCALEB: B = h1 (unscaled), reg-staged with dinv[k] from an LDS table.
// !SCALEB: B = hs2T (pre-scaled), pure global_load_lds staging.
template <bool SCALEB>
__global__ __launch_bounds__(512) void gemm_big(const unsigned short* __restrict__ A,
                                                const unsigned short* __restrict__ B,
                                                const float* __restrict__ dinv,
                                                float* __restrict__ P) {
  __shared__ unsigned short lds[2 * BUFHW + 4096];  // 104 KB (incl. 8 KB dinv table)
  float* DV = (float*)(lds + DVHW);
  const int tid = threadIdx.x;
  const int mt = blockIdx.x & 63;
  const int z = blockIdx.x >> 6;
  const int m0 = mt * BM2;

  const int w = tid >> 6, l = tid & 63;
  const int lrow = l >> 3, col8 = l & 7;
  const int swz = (col8 * 16) ^ (lrow << 4);  // pre-swizzled byte-in-row (matches read XOR)

  const char* Asrc[2];
#pragma unroll
  for (int j = 0; j < 2; ++j) {
    int ra = w * 16 + j * 8 + lrow;
    Asrc[j] = (const char*)(A + (size_t)(m0 + ra) * KFULL + (size_t)z * KQ) + swz;
  }
  auto stageA = [&](int buf, int t) {  // 2 global_load_lds per thread
    unsigned short* L = lds + buf * BUFHW;
#pragma unroll
    for (int j = 0; j < 2; ++j)
      gload16(Asrc[j] + (size_t)t * (BK2 * 2), L + (w * 16 + j * 8) * 64);
  };

  // --- B staging (two variants) ---
  const char* Bsrc[4];
  const int sr = tid >> 3, sc = (tid & 7) * 8;
#pragma unroll
  for (int j = 0; j < 4; ++j) {
    if (SCALEB) {
      // reg-stage source rows sr+64j, natural layout
      Bsrc[j] = (const char*)(B + (size_t)(sr + 64 * j) * KFULL + (size_t)z * KQ + sc);
    } else {
      int rb = j * 64 + w * 8 + lrow;
      Bsrc[j] = (const char*)(B + (size_t)rb * KFULL + (size_t)z * KQ) + swz;
    }
  }
  s16x8 br[4];
  auto loadB = [&](int t) {  // 4 × 16B global loads to regs
#pragma unroll
    for (int j = 0; j < 4; ++j)
      br[j] = *(const s16x8*)(Bsrc[j] + (size_t)t * (BK2 * 2));
  };
  auto writeB = [&](int buf, int t) {  // scale by dinv + pack + swizzled ds_write
    unsigned short* L = lds + buf * BUFHW + BM2 * BK2;
    f32x4 d0 = *(const f32x4*)(DV + t * 64 + sc);
    f32x4 d1 = *(const f32x4*)(DV + t * 64 + sc + 4);
#pragma unroll
    for (int j = 0; j < 4; ++j) {
      int r = sr + 64 * j;
      s16x8 o;
#pragma unroll
      for (int e = 0; e < 4; ++e) {
        o[e] = (short)f2bf(bf2f((unsigned short)br[j][e]) * d0[e]);
        o[e + 4] = (short)f2bf(bf2f((unsigned short)br[j][e + 4]) * d1[e]);
      }
      *(s16x8*)(L + ((r * 64 + sc) ^ ((r & 7) << 3))) = o;
    }
  };
  auto stageB_dma = [&](int buf, int t) {  // 4 global_load_lds per thread
    unsigned short* L = lds + buf * BUFHW + BM2 * BK2;
#pragma unroll
    for (int j = 0; j < 4; ++j)
      gload16(Bsrc[j] + (size_t)t * (BK2 * 2), L + j * 4096 + w * 512);
  };

  const int wr = w >> 2, wc = w & 3;
  const int g = l >> 4, lr = l & 15;
  int aidx[4][2], bidx[4][2];
#pragma unroll
  for (int m = 0; m < 4; ++m)
#pragma unroll
    for (int ks = 0; ks < 2; ++ks) {
      int r = wr * 64 + m * 16 + lr;
      aidx[m][ks] = r * 64 + ((ks * 32 + g * 8) ^ ((r & 7) << 3));
    }
#pragma unroll
  for (int n = 0; n < 4; ++n)
#pragma unroll
    for (int ks = 0; ks < 2; ++ks) {
      int r = wc * 64 + n * 16 + lr;
      bidx[n][ks] = BM2 * BK2 + r * 64 + ((ks * 32 + g * 8) ^ ((r & 7) << 3));
    }

  f32x4 acc[4][4];
#pragma unroll
  for (int m = 0; m < 4; ++m)
#pragma unroll
    for (int n = 0; n < 4; ++n) {
      f32x4 zz = {0.f, 0.f, 0.f, 0.f};
      acc[m][n] = zz;
    }

  // ---- prologue ----
  if (SCALEB) {
    f32x4 dv = *(const f32x4*)(dinv + (size_t)z * KQ + tid * 4);
    *(f32x4*)(DV + tid * 4) = dv;
  }
  stageA(0, 0);
  if (SCALEB) loadB(0); else stageB_dma(0, 0);
  __syncthreads();  // drains everything; dinv table visible
  if (SCALEB) writeB(0, 0);

  const int nt = KQ / BK2;  // 32
  for (int t = 0; t < nt; ++t) {
    int cur = t & 1;
    if (SCALEB) {
      if (t + 1 < nt) {
        loadB(t + 1);
        asm volatile("s_waitcnt vmcnt(4)" ::: "memory");  // A(t) done; B(t+1) in flight
      } else {
        asm volatile("s_waitcnt vmcnt(0)" ::: "memory");
      }
    } else {
      asm volatile("s_waitcnt vmcnt(0)" ::: "memory");  // stage(t) done (issued 1.3 iters ago)
    }
    asm volatile("s_waitcnt lgkmcnt(0)" ::: "memory");
    asm volatile("s_barrier" ::: "memory");
    __builtin_amdgcn_sched_barrier(0);

    const unsigned short* L = lds + cur * BUFHW;
    s16x8 af[4][2], bfr[4][2];
#pragma unroll
    for (int m = 0; m < 4; ++m)
#pragma unroll
      for (int ks = 0; ks < 2; ++ks) af[m][ks] = *(const s16x8*)(L + aidx[m][ks]);
#pragma unroll
    for (int n = 0; n < 4; ++n)
#pragma unroll
      for (int ks = 0; ks < 2; ++ks) bfr[n][ks] = *(const s16x8*)(L + bidx[n][ks]);

    // issue next tile's stage BEFORE the MFMA cluster (latency hidden under MFMA)
    if (t + 1 < nt) {
      stageA(cur ^ 1, t + 1);
      if (!SCALEB) stageB_dma(cur ^ 1, t + 1);
    }

    __builtin_amdgcn_s_setprio(1);
#pragma unroll
    for (int m = 0; m < 4; ++m)
#pragma unroll
      for (int n = 0; n < 4; ++n)
#pragma unroll
        for (int ks = 0; ks < 2; ++ks)
          acc[m][n] = __builtin_amdgcn_mfma_f32_16x16x32_bf16(af[m][ks], bfr[n][ks],
                                                              acc[m][n], 0, 0, 0);
    __builtin_amdgcn_s_setprio(0);

    if (SCALEB && t + 1 < nt) {
      asm volatile("s_waitcnt vmcnt(2)" ::: "memory");  // B(t+1) regs ready; A(t+1) in flight
      writeB(cur ^ 1, t + 1);
    }
  }

  float* Pz = P + (size_t)z * 8192 * 256;
#pragma unroll
  for (int m = 0; m < 4; ++m)
#pragma unroll
    for (int n = 0; n < 4; ++n) {
      int col = wc * 64 + n * 16 + lr;
#pragma unroll
      for (int r = 0; r < 4; ++r) {
        int row = m0 + wr * 64 + m * 16 + g * 4 + r;
        Pz[(size_t)row * 256 + col] = acc[m][n][r];
      }
    }
}

// ---------------- reduce1: hln = LN(GELU((ΣPz)*dinv[row])), bf16 out ----------------
__global__ __launch_bounds__(256) void reduce_ln(const float* __restrict__ P,
                                                 const float* __restrict__ dinv,
                                                 const float* __restrict__ gamma,
                                                 const float* __restrict__ beta,
                                                 unsigned short* __restrict__ hln) {
  const size_t ZSTR = (size_t)8192 * 256;
  int row = blockIdx.x * 4 + (threadIdx.x >> 6);
  int l = threadIdx.x & 63;
  const float* p = P + (size_t)row * 256 + l * 4;
  f32x4 a = *(const f32x4*)p;
  f32x4 b = *(const f32x4*)(p + ZSTR);
  f32x4 c = *(const f32x4*)(p + 2 * ZSTR);
  f32x4 d = *(const f32x4*)(p + 3 * ZSTR);
  float di = dinv[row];
  float gl[4];
  float s = 0.f, q = 0.f;
#pragma unroll
  for (int j = 0; j < 4; ++j) {
    float v = (a[j] + b[j] + c[j] + d[j]) * di;
    float gv = 0.5f * v * (1.0f + erff(v * 0.70710678118654752440f));
    gl[j] = gv;
    s += gv;
    q += gv * gv;
  }
#pragma unroll
  for (int off = 1; off < 64; off <<= 1) {
    s += __shfl_xor(s, off, 64);
    q += __shfl_xor(q, off, 64);
  }
  float mu = s * (1.0f / 256.0f);
  float var = q * (1.0f / 256.0f) - mu * mu;
  float rs = rsqrtf(fmaxf(var, 0.f) + 1e-6f);
  f32x4 gm = *(const f32x4*)(gamma + l * 4);
  f32x4 bt = *(const f32x4*)(beta + l * 4);
  unsigned short o4[4];
#pragma unroll
  for (int j = 0; j < 4; ++j)
    o4[j] = f2bf((gl[j] - mu) * rs * gm[j] + bt[j]);
  *(unsigned long long*)(hln + (size_t)row * 256 + l * 4) =
      *(const unsigned long long*)o4;
}

// ---------------- reduce2: out fp32 = (ΣPz)*dinv[row] ----------------
__global__ __launch_bounds__(256) void reduce_sc(const float* __restrict__ P,
                                                 const float* __restrict__ dinv,
                                                 float* __restrict__ out) {
  const size_t ZSTR = (size_t)8192 * 256;
  size_t i = ((size_t)blockIdx.x * 256 + threadIdx.x) * 4;
  int row = (int)(i >> 8);
  f32x4 a = *(const f32x4*)(P + i);
  f32x4 b = *(const f32x4*)(P + ZSTR + i);
  f32x4 c = *(const f32x4*)(P + 2 * ZSTR + i);
  f32x4 d = *(const f32x4*)(P + 3 * ZSTR + i);
  float di = dinv[row];
  f32x4 o;
#pragma unroll
  for (int j = 0; j < 4; ++j) o[j] = (a[j] + b[j] + c[j] + d[j]) * di;
  *(f32x4*)(out + i) = o;
}

// ---------------- GEMM6: hs2T = bf16((hln @ W2 + b2)^T * dinv[col]) ----------------
__global__ __launch_bounds__(256) void gemm6_k(const float* __restrict__ W2T,
                                               const unsigned short* __restrict__ hln,
                                               unsigned short* __restrict__ hs2T,
                                               const float* __restrict__ b2,
                                               const float* __restrict__ dinv) {
  __shared__ unsigned short lds[2 * LDS_TILE];
  gemm_small<false, 1>(blockIdx.x, lds, W2T, hln, hs2T, b2, dinv, 256, 8192, 256);
}

// ---------------- launch ----------------
extern "C" void kernel_launch(void* const* d_in, const int* in_sizes, int n_in,
                              void* d_out, int out_size, void* d_ws, size_t ws_size,
                              hipStream_t stream) {
  (void)in_sizes; (void)n_in; (void)out_size; (void)ws_size;
  const float* x     = (const float*)d_in[0];
  const float* adj   = (const float*)d_in[1];
  const float* W1    = (const float*)d_in[2];
  const float* b1    = (const float*)d_in[3];
  const float* W2    = (const float*)d_in[4];
  const float* b2    = (const float*)d_in[5];
  const float* gamma = (const float*)d_in[6];
  const float* beta  = (const float*)d_in[7];
  float* out = (float*)d_out;

  char* ws = (char*)d_ws;
  float* dinv          = (float*)ws;                           // 32 KB
  float* W1T           = (float*)(ws + (64 << 10));            // 512 KB [256][512]
  float* W2T           = (float*)(ws + (640 << 10));           // 256 KB [256][256]
  unsigned short* h1   = (unsigned short*)(ws + (1 << 20));    // 4 MB [256][8192] (pre-dinv)
  unsigned short* hln  = (unsigned short*)(ws + (16 << 20));   // 4 MB [8192][256]
  unsigned short* hs2T = (unsigned short*)(ws + (24 << 20));   // 4 MB [256][8192]
  float* P             = (float*)(ws + (32 << 20));            // 32 MB [4][8192][256]
  unsigned short* adjh = (unsigned short*)(ws + (64 << 20));   // 128 MB [8192][8192] (adj+I)

  // 0) weight transposes (merged)
  transW<<<48, 256, 0, stream>>>(W1, W2, W1T, W2T);
  // 1) gemm3 (h1 bf16) + adj->bf16(+I) + rowsum->dinv, fused
  prep<<<4352, 256, 0, stream>>>(adj, x, W1T, b1, adjh, dinv, h1);
  // 2) P = split-K=4 partials of (adj+I) @ (h1*dinv)  [dinv fused into B staging]
  gemm_big<true><<<256, 512, 0, stream>>>(adjh, h1, dinv, P);
  // 3) hln = LN(GELU((ΣPz)*dinv[row]))
  reduce_ln<<<2048, 256, 0, stream>>>(P, dinv, gamma, beta, hln);
  // 4) hs2T = bf16((hln @ W2 + b2)^T * dinv[node])
  gemm6_k<<<256, 256, 0, stream>>>(W2T, hln, hs2T, b2, dinv);
  // 5) P = split-K=4 partials of (adj+I) @ hs2
  gemm_big<false><<<256, 512, 0, stream>>>(adjh, hs2T, dinv, P);
  // 6) out = (ΣPz)*dinv[row]
  reduce_sc<<<2048, 256, 0, stream>>>(P, dinv, out);
}